// Round 1
// baseline (331.162 us; speedup 1.0000x reference)
//
#include <hip/hip_runtime.h>

#define N_VEC   131072
#define D       64
#define KCODES  1024
#define KC      128            // codes per LDS chunk
#define BLK     256
#define M       2              // z-vectors per thread
#define VPB     (BLK * M)      // 512 vectors per block

// ws layout:
// [0, 4096)        int   counts[1024]
// [4096, 4100)     float sse
// [5120, 9216)     float esq[1024]

__device__ __forceinline__ float4 f4fma(float4 a, float4 b, float4 c) {
    return make_float4(fmaf(a.x, b.x, c.x), fmaf(a.y, b.y, c.y),
                       fmaf(a.z, b.z, c.z), fmaf(a.w, b.w, c.w));
}
__device__ __forceinline__ float f4rsum(float4 a) {
    return (a.x + a.y) + (a.z + a.w);
}

__global__ void esq_kernel(const float* __restrict__ cb, float* __restrict__ esq) {
    int k = blockIdx.x * blockDim.x + threadIdx.x;
    if (k < KCODES) {
        const float4* c4 = reinterpret_cast<const float4*>(cb + k * D);
        float4 p = make_float4(0.f, 0.f, 0.f, 0.f);
        #pragma unroll
        for (int i = 0; i < D / 4; ++i) {
            float4 v = c4[i];
            p = f4fma(v, v, p);
        }
        esq[k] = f4rsum(p);
    }
}

__launch_bounds__(BLK, 1)
__global__ void vq_main(const float* __restrict__ z_e, const float* __restrict__ cb,
                        const float* __restrict__ esq,
                        float* __restrict__ zq_out, float* __restrict__ idx_out,
                        float* __restrict__ sse, int* __restrict__ counts) {
    __shared__ float4 scb[KC * (D / 4)];   // 32 KB codebook chunk
    __shared__ float  sesq[KC];
    __shared__ int    shist[KCODES];       // 4 KB per-block histogram
    __shared__ float  sred[BLK / 64];

    const int tid = threadIdx.x;

    for (int i = tid; i < KCODES; i += BLK) shist[i] = 0;

    const int n0 = blockIdx.x * VPB + tid;
    const int n1 = n0 + BLK;

    // load both z vectors into registers (64 floats each)
    float4 zA[16], zB[16];
    const float4* zA4 = reinterpret_cast<const float4*>(z_e + (size_t)n0 * D);
    const float4* zB4 = reinterpret_cast<const float4*>(z_e + (size_t)n1 * D);
    #pragma unroll
    for (int i = 0; i < 16; ++i) { zA[i] = zA4[i]; zB[i] = zB4[i]; }

    float4 pA = make_float4(0.f, 0.f, 0.f, 0.f);
    float4 pB = make_float4(0.f, 0.f, 0.f, 0.f);
    #pragma unroll
    for (int i = 0; i < 16; ++i) { pA = f4fma(zA[i], zA[i], pA); pB = f4fma(zB[i], zB[i], pB); }
    const float zsqA = f4rsum(pA);
    const float zsqB = f4rsum(pB);

    float bestA = INFINITY, bestB = INFINITY;
    int   biA = 0, biB = 0;

    for (int kcbase = 0; kcbase < KCODES; kcbase += KC) {
        __syncthreads();   // protect LDS reuse (and hist zero on first iter)
        // stage 128 codes -> LDS (coalesced float4)
        const float4* g4 = reinterpret_cast<const float4*>(cb + (size_t)kcbase * D);
        #pragma unroll
        for (int i = 0; i < (KC * D / 4) / BLK; ++i)   // 8 iters
            scb[i * BLK + tid] = g4[i * BLK + tid];
        if (tid < KC) sesq[tid] = esq[kcbase + tid];
        __syncthreads();

        #pragma unroll 4
        for (int kk = 0; kk < KC; ++kk) {
            float4 sA = make_float4(0.f, 0.f, 0.f, 0.f);
            float4 sB = make_float4(0.f, 0.f, 0.f, 0.f);
            #pragma unroll
            for (int i = 0; i < 16; ++i) {
                float4 e = scb[kk * 16 + i];   // LDS broadcast
                sA = f4fma(zA[i], e, sA);
                sB = f4fma(zB[i], e, sB);
            }
            // replicate reference rounding: t1 = fp32(zsq + esq); d = fp32(t1 - 2*dot)
            float t1A = zsqA + sesq[kk];
            float t1B = zsqB + sesq[kk];
            float dA = fmaf(-2.0f, f4rsum(sA), t1A);
            float dB = fmaf(-2.0f, f4rsum(sB), t1B);
            if (dA < bestA) { bestA = dA; biA = kcbase + kk; }   // strict <: lowest-index tie-break
            if (dB < bestB) { bestB = dB; biB = kcbase + kk; }
        }
    }

    // histogram
    atomicAdd(&shist[biA], 1);
    atomicAdd(&shist[biB], 1);

    // indices as float
    idx_out[n0] = (float)biA;
    idx_out[n1] = (float)biB;

    // gather z_q (exact codebook values, matches reference take())
    {
        const float4* cA = reinterpret_cast<const float4*>(cb + (size_t)biA * D);
        const float4* cB = reinterpret_cast<const float4*>(cb + (size_t)biB * D);
        float4* oA = reinterpret_cast<float4*>(zq_out + (size_t)n0 * D);
        float4* oB = reinterpret_cast<float4*>(zq_out + (size_t)n1 * D);
        #pragma unroll
        for (int i = 0; i < 16; ++i) { oA[i] = cA[i]; oB[i] = cB[i]; }
    }

    // sse reduction: best distance == ||z - z_q||^2
    float v = bestA + bestB;
    #pragma unroll
    for (int off = 32; off > 0; off >>= 1) v += __shfl_down(v, off);
    if ((tid & 63) == 0) sred[tid >> 6] = v;
    __syncthreads();
    if (tid == 0) {
        float t = (sred[0] + sred[1]) + (sred[2] + sred[3]);
        atomicAdd(sse, t);
    }

    __syncthreads();   // all shist atomics done
    for (int i = tid; i < KCODES; i += BLK) {
        int c = shist[i];
        if (c) atomicAdd(&counts[i], c);
    }
}

__global__ void finalize_kernel(const int* __restrict__ counts, const float* __restrict__ sse,
                                float* __restrict__ out_loss, float* __restrict__ out_perp) {
    __shared__ float red[256];
    int tid = threadIdx.x;
    float h = 0.f;
    for (int k = tid; k < KCODES; k += 256) {
        float p = (float)counts[k] / (float)N_VEC;
        h += p * logf(p + 1e-12f);
    }
    red[tid] = h;
    __syncthreads();
    for (int s = 128; s > 0; s >>= 1) {
        if (tid < s) red[tid] += red[tid + s];
        __syncthreads();
    }
    if (tid == 0) {
        out_loss[0] = 1.25f * sse[0] / 8388608.0f;   // (1+BETA) * mean
        out_perp[0] = expf(-red[0]);
    }
}

extern "C" void kernel_launch(void* const* d_in, const int* in_sizes, int n_in,
                              void* d_out, int out_size, void* d_ws, size_t ws_size,
                              hipStream_t stream) {
    const float* z_e = (const float*)d_in[0];
    const float* cb  = (const float*)d_in[1];

    float* out  = (float*)d_out;
    float* zq   = out;
    float* idxo = out + (size_t)N_VEC * D;          // 8388608
    float* loss = idxo + N_VEC;                     // +131072
    float* perp = loss + 1;

    int*   counts = (int*)d_ws;
    float* sse    = (float*)((char*)d_ws + 4096);
    float* esq    = (float*)((char*)d_ws + 5120);

    hipMemsetAsync(d_ws, 0, 5120, stream);          // zero counts + sse each call
    esq_kernel<<<4, 256, 0, stream>>>(cb, esq);
    vq_main<<<N_VEC / VPB, BLK, 0, stream>>>(z_e, cb, esq, zq, idxo, sse, counts);
    finalize_kernel<<<1, 256, 0, stream>>>(counts, sse, loss, perp);
}